// Round 2
// baseline (951.926 us; speedup 1.0000x reference)
//
#include <hip/hip_runtime.h>

// NeuralODE SSP-RK3, z:[32,16,8192] fp32, W:[16,16,5], 100 steps, h=t/100.
// Structure: 20 dispatches x 5 fused RK steps (15 stages) via LDS halo
// recompute; transposed fp32 state [b][x][ch]; conv = 3x
// mfma_f32_16x16x32_bf16 per 16-col tile; conv inputs/weights bf16,
// state/pointwise fp32 in named registers; BC via in-wave shuffles.
// R12/R13 FAILED: neither amdgpu_waves_per_eu(4,4), __launch_bounds__(256,4)
// nor a 40KB LDS pad moved VGPR_Count off 64 -> RA budget is pinned at 64 on
// this toolchain; the 52-dword state (kz0..4+kf0..4+af0..2) spilled to
// scratch (WRITE excess 52 MiB/dispatch = 208B/thread, evicted dirty).
// R14 CHANGE (single variable): fit the state INSIDE 64 VGPRs instead.
// TX 256->128: slab 192 cols = 12 tiles, 3 tiles/thread -> state =
// kz0..2+kf0..2+af0..2 = 36 dwords; peak live ~62. Cost: halo overhead
// 1.25x -> 1.5x MFMA (MfmaUtil was 10%, cheap); grid 2048 blocks = 8/CU
// exactly resident (12KB LDS). Pad + waves_per_eu reverted (would now cap
// residency). Success signal: WRITE_SIZE 69632 -> ~16900 KB, dur -> ~600us.

#define NCH    16
#define LL     8192
#define TX     128
#define HALOC  32
#define SLABC  192          // 12 tiles of 16 cols; global x = x0 - 32 + s
#define NBX    64
#define NB     32
#define NSTEPS 100
#define SPK    5
#define NKER   (NSTEPS / SPK)

typedef __bf16 bf16x8 __attribute__((ext_vector_type(8)));
typedef __bf16 bf16x4 __attribute__((ext_vector_type(4)));
typedef float  f32x4  __attribute__((ext_vector_type(4)));

__device__ __forceinline__ int ldsIdx(int col, int ch) {
  return col * NCH + (ch ^ ((col & 4) << 1));
}

__global__ __launch_bounds__(256) void transpose_kernel(const float* __restrict__ in,
                                                        float* __restrict__ out) {
  const int b = blockIdx.y;
  const int x = blockIdx.x * 256 + threadIdx.x;
  const float* __restrict__ ib = in + (size_t)b * NCH * LL;
  float* __restrict__ ob = out + (size_t)b * NCH * LL;
  float v[NCH];
#pragma unroll
  for (int c = 0; c < NCH; ++c) v[c] = ib[c * LL + x];
#pragma unroll
  for (int c = 0; c < NCH; c += 4)
    *(float4*)(ob + (size_t)x * NCH + c) = make_float4(v[c], v[c+1], v[c+2], v[c+3]);
}

__device__ __forceinline__ bf16x8 mkA(const float* __restrict__ W, int c, int g, int n) {
  const int kk = c * 2 + (g >> 1);
  bf16x8 a;
#pragma unroll
  for (int j = 0; j < 8; ++j) {
    const int i = (g & 1) * 8 + j;
    a[j] = (__bf16)((kk < 5) ? W[n * (NCH * 5) + i * 5 + kk] : 0.0f);
  }
  return a;
}

__device__ __forceinline__ f32x4 ldState(const float* __restrict__ zb, int x0,
                                         int t, int n, int g) {
  int gx = x0 - HALOC + 16 * t + n;
  gx = min(max(gx, 0), LL - 1);
  return *(const f32x4*)(zb + (size_t)gx * NCH + g * 4);
}

// One 16-col tile of one RK stage. MODE 0: bf16 -> WS(LDS). MODE 1: global
// store (transposed fp32, or row-major if finalKer). UPDZ: kz <- v.
template<int MODE, bool UPDZ>
__device__ __forceinline__ void tileStage(
    int t, f32x4& KZ, f32x4& KF, float az, float ak, float agh,
    const __bf16* __restrict__ RS, __bf16* __restrict__ WS,
    bf16x8 af0, bf16x8 af1, bf16x8 af2,
    int lane, int g, int n, bool leftE, bool rightE,
    float* __restrict__ ob, int x0, int finalKer)
{
  f32x4 acc = {0.f, 0.f, 0.f, 0.f};
#pragma unroll
  for (int c = 0; c < 3; ++c) {
    const int kk = c * 2 + (g >> 1);
    int s = 16 * t + n + kk - 2;         // read col = write col + (kk-2)
    s = min(max(s, 0), SLABC - 1);
    const bf16x8 bfrag = *(const bf16x8*)(&RS[ldsIdx(s, (g & 1) * 8)]);
    const bf16x8 a = (c == 0) ? af0 : (c == 1) ? af1 : af2;
    acc = __builtin_amdgcn_mfma_f32_16x16x32_bf16(a, bfrag, acc, 0, 0, 0);
  }
  f32x4 v;
#pragma unroll
  for (int r = 0; r < 4; ++r) v[r] = az * KZ[r] + ak * KF[r] + agh * acc[r];

  // BC: x 0..9 <- x=10 (t=2, lane n=10); x 8182..8191 <- x=8181 (t=9, n=5)
  if (leftE && t == 2) {
#pragma unroll
    for (int r = 0; r < 4; ++r) {
      const float sv = __shfl(v[r], (lane & 48) | 10, 64);
      if (n < 10) v[r] = sv;
    }
  }
  if (rightE && t == 9) {
#pragma unroll
    for (int r = 0; r < 4; ++r) {
      const float sv = __shfl(v[r], (lane & 48) | 5, 64);
      if (n > 5) v[r] = sv;
    }
  }

  KF = v;
  if (UPDZ) KZ = v;

  if (MODE == 0) {
    bf16x4 bv = { (__bf16)v[0], (__bf16)v[1], (__bf16)v[2], (__bf16)v[3] };
    *(bf16x4*)(&WS[ldsIdx(16 * t + n, g * 4)]) = bv;
  } else {
    if (t >= 2 && t <= 9) {              // interior: gx in [x0, x0+128)
      const int xg = x0 - HALOC + 16 * t + n;
      if (!finalKer) {
        *(f32x4*)(ob + (size_t)xg * NCH + g * 4) = v;
      } else {
#pragma unroll
        for (int r = 0; r < 4; ++r) ob[(size_t)(g * 4 + r) * LL + xg] = v[r];
      }
    }
  }
}

#define STAGE(az, ak, agh, UPDZ, MODE)                                          \
  do {                                                                          \
    const __bf16* RS_ = S[rb];                                                  \
    __bf16* WS_ = S[rb ^ 1];                                                    \
    tileStage<MODE, UPDZ>(wv + 0, kz0, kf0, az, ak, agh, RS_, WS_, af0, af1,    \
                          af2, lane, g, n, leftE, rightE, ob, x0, finalKer);    \
    tileStage<MODE, UPDZ>(wv + 4, kz1, kf1, az, ak, agh, RS_, WS_, af0, af1,    \
                          af2, lane, g, n, leftE, rightE, ob, x0, finalKer);    \
    tileStage<MODE, UPDZ>(wv + 8, kz2, kf2, az, ak, agh, RS_, WS_, af0, af1,    \
                          af2, lane, g, n, leftE, rightE, ob, x0, finalKer);    \
  } while (0)

__global__ __launch_bounds__(256)
void multistep_kernel(
    const float* __restrict__ zin,   // fp32 transposed [b][x][ch]
    float* __restrict__ zout,        // fp32 transposed (row-major if finalKer)
    const float* __restrict__ W,     // [o][i][k] 16x16x5
    const int* __restrict__ tptr, int finalKer)
{
  __shared__ __align__(16) __bf16 S[2][SLABC * NCH];

  const int b = blockIdx.y, bx = blockIdx.x;
  const int x0 = bx * TX;
  const bool leftE = (bx == 0), rightE = (bx == NBX - 1);
  const float h = (float)(*tptr) / (float)NSTEPS;
  const int tid = threadIdx.x, lane = tid & 63, wv = tid >> 6;
  const int g = lane >> 4, n = lane & 15;

  const float* __restrict__ zb = zin + (size_t)b * NCH * LL;
  float* __restrict__ ob = zout + (size_t)b * NCH * LL;

  const bf16x8 af0 = mkA(W, 0, g, n);
  const bf16x8 af1 = mkA(W, 1, g, n);
  const bf16x8 af2 = mkA(W, 2, g, n);

  // Load z slab -> S[0] (bf16, swizzled); coalesced (4 threads per 64B line).
  for (int q = tid; q < SLABC * 4; q += 256) {
    const int s = q >> 2, cg = (q & 3) * 4;
    int gx = x0 - HALOC + s;
    gx = min(max(gx, 0), LL - 1);
    const float4 v = *(const float4*)(zb + (size_t)gx * NCH + cg);
    bf16x4 bv = { (__bf16)v.x, (__bf16)v.y, (__bf16)v.z, (__bf16)v.w };
    *(bf16x4*)(&S[0][ldsIdx(s, cg)]) = bv;
  }

  // fp32 state in named registers: thread owns (x=16t+n, ch 4g..4g+3), t=wv+4ti.
  f32x4 kz0 = ldState(zb, x0, wv + 0, n, g);
  f32x4 kz1 = ldState(zb, x0, wv + 4, n, g);
  f32x4 kz2 = ldState(zb, x0, wv + 8, n, g);
  f32x4 kf0 = {0.f,0.f,0.f,0.f}, kf1 = kf0, kf2 = kf0;
  __syncthreads();

  const float c13 = 1.0f / 3.0f, c23 = 2.0f / 3.0f;
  int rb = 0;
#pragma unroll 1
  for (int sp = 0; sp < SPK; ++sp) {
    STAGE(1.0f, 0.0f, h, false, 0);
    __syncthreads(); rb ^= 1;
    STAGE(0.75f, 0.25f, 0.25f * h, false, 0);
    __syncthreads(); rb ^= 1;
    if (sp != SPK - 1) {
      STAGE(c13, c23, c23 * h, true, 0);
      __syncthreads(); rb ^= 1;
    } else {
      STAGE(c13, c23, c23 * h, true, 1);
    }
  }
}

extern "C" void kernel_launch(void* const* d_in, const int* in_sizes, int n_in,
                              void* d_out, int out_size, void* d_ws, size_t ws_size,
                              hipStream_t stream) {
  const float* z0 = (const float*)d_in[0];
  const float* W  = (const float*)d_in[1];
  const int*   t  = (const int*)d_in[2];

  float* Q = (float*)d_out;   // transposed intermediate; final row-major dest
  float* P = (float*)d_ws;    // 16 MiB scratch

  dim3 grid(32, NB), block(256);
  transpose_kernel<<<grid, block, 0, stream>>>(z0, Q);

  dim3 mgrid(NBX, NB);
  for (int k = 1; k <= NKER; ++k) {
    if (k & 1) multistep_kernel<<<mgrid, block, 0, stream>>>(Q, P, W, t, 0);
    else       multistep_kernel<<<mgrid, block, 0, stream>>>(P, Q, W, t, k == NKER);
  }
}

// Round 3
// 801.164 us; speedup vs baseline: 1.1882x; 1.1882x over previous
//
#include <hip/hip_runtime.h>

// NeuralODE SSP-RK3, z:[32,16,8192] fp32, W:[16,16,5], 100 steps, h=t/100.
// R14 POST-MORTEM: spill eliminated (WRITE 69632->16384 KB) but dur/dispatch
// pinned at 53.3us across 3 structurally different kernels -> the floor is
// the 15 barrier-serialized stages (latency chain), not any per-stage cost.
// R15 CHANGE: the RHS is LINEAR, so 5 RK3 steps fuse into ONE 61-tap conv:
//   z' = z + S5 z,  S5 = (I+T')^5 - I,  T' = G + G^2/2 + G^3/6,  G = h*conv(W)
// Interior blocks (62/64): single conv stage per dispatch - no inter-stage
// barriers, no LDS round-trips, no halo recompute. Clamp-affected region is
// <= 37 cols/edge < TX=128, so the 2 edge blocks keep the verified R14
// 15-stage path verbatim. S5 taps built on-device by tiny setup kernels
// (conv-kernel algebra in fp32 -> bf16 A-frag table in __device__ globals).
// Numerics: z bf16-rounded 1x per 5 steps (was 3x/step); identity stays fp32.
// Predicted: dispatch 53.3 -> 10-16us, total ~300us, MfmaUtil 13->40%.

#define NCH    16
#define LL     8192
#define TX     128
#define HALOC  32
#define SLABC  192          // edge path: 12 tiles of 16 cols
#define NBX    64
#define NB     32
#define NSTEPS 100
#define SPK    5
#define NKER   (NSTEPS / SPK)

#define RAD    30           // fused-operator radius = 6*SPK
#define NCHUNK 31           // 62 taps (61 real + 1 zero pad) / 2 per K-chunk
#define ISLAB  190          // interior slab cols: o(0..127)+k(0..61) -> 0..188

typedef __bf16 bf16x8 __attribute__((ext_vector_type(8)));
typedef __bf16 bf16x4 __attribute__((ext_vector_type(4)));
typedef float  f32x4  __attribute__((ext_vector_type(4)));

// ---- setup: conv-kernel algebra in __device__ globals (fp32) ----
__device__ __align__(16) float g_G [ 5*256];   // h*F
__device__ __align__(16) float g_G2[ 9*256];   // G^2
__device__ __align__(16) float g_Tp[13*256];   // first G^3, then T'
__device__ __align__(16) float g_T2[25*256];   // T'^2
__device__ __align__(16) float g_T3[37*256];   // T'^3
__device__ __align__(16) float g_T4[49*256];   // T'^4
__device__ __align__(16) float g_T5[61*256];   // T'^5
__device__ __align__(16) __bf16 g_Sfrag[NCHUNK*64*8];  // A-frag table [c][lane][8]

__global__ void build_G(const float* __restrict__ W, const int* __restrict__ tptr) {
  const float h = (float)(*tptr) / (float)NSTEPS;
  const int o = threadIdx.x >> 4, i = threadIdx.x & 15;
#pragma unroll
  for (int k = 0; k < 5; ++k)
    g_G[k*256 + o*16 + i] = h * W[o*80 + i*5 + k];
}

// C_d = sum_{a+b=d} A_a * B_b (16x16 matrix product per pair). grid.x = 2*(ra+rb)+1.
__global__ void compose_k(int mode) {
  const float* A; int ra; const float* B; int rb; float* C;
  switch (mode) {
    case 0:  A = g_G;  ra = 2;  B = g_G;  rb = 2; C = g_G2; break; //  9 taps
    case 1:  A = g_G2; ra = 4;  B = g_G;  rb = 2; C = g_Tp; break; // G^3, 13
    case 2:  A = g_Tp; ra = 6;  B = g_Tp; rb = 6; C = g_T2; break; // 25
    case 3:  A = g_T2; ra = 12; B = g_Tp; rb = 6; C = g_T3; break; // 37
    case 4:  A = g_T3; ra = 18; B = g_Tp; rb = 6; C = g_T4; break; // 49
    default: A = g_T4; ra = 24; B = g_Tp; rb = 6; C = g_T5; break; // 61
  }
  const int rc = ra + rb;
  const int d = (int)blockIdx.x - rc;
  const int o = threadIdx.x >> 4, i = threadIdx.x & 15;
  float acc = 0.f;
  for (int a = -ra; a <= ra; ++a) {
    const int b = d - a;
    if (b < -rb || b > rb) continue;
    const float* Am = A + (a+ra)*256 + o*16;
    const float* Bm = B + (b+rb)*256 + i;
#pragma unroll
    for (int j = 0; j < 16; ++j) acc += Am[j] * Bm[j*16];
  }
  C[(size_t)blockIdx.x*256 + o*16 + i] = acc;
}

__global__ void build_Tp() {   // g_Tp holds G^3; T' = G^3/6 + pad(G2)/2 + pad(G)
  const int o = threadIdx.x >> 4, i = threadIdx.x & 15;
#pragma unroll
  for (int k = 0; k < 13; ++k) {
    const int d = k - 6;
    float v = g_Tp[k*256 + o*16 + i] * (1.f/6.f);
    if (d >= -4 && d <= 4) v += 0.5f * g_G2[(d+4)*256 + o*16 + i];
    if (d >= -2 && d <= 2) v += g_G[(d+2)*256 + o*16 + i];
    g_Tp[k*256 + o*16 + i] = v;
  }
}

__device__ __forceinline__ float padread(const float* M, int r, int d, int oi) {
  return (d >= -r && d <= r) ? M[(d+r)*256 + oi] : 0.f;
}

// S5 = 5T' + 10T'^2 + 10T'^3 + 5T'^4 + T'^5, packed as bf16 MFMA A-frags:
// g_Sfrag[c][lane=g*16+n][j] = S5[tap k=2c+(g>>1)][o=n][i=(g&1)*8+j], k=61 -> 0.
__global__ void pack_S() {
  const int c = blockIdx.x;
  const int lane = threadIdx.x & 63;
  const int jj = (threadIdx.x >> 6) * 2;
  const int gg = lane >> 4, n = lane & 15;
  const int k = 2*c + (gg >> 1);
  const int d = k - RAD;
#pragma unroll
  for (int u = 0; u < 2; ++u) {
    const int j = jj + u;
    const int i = (gg & 1)*8 + j;
    const int oi = n*16 + i;
    float v = 0.f;
    if (k <= 60) {
      v = 5.f  * padread(g_Tp,  6, d, oi)
        + 10.f * padread(g_T2, 12, d, oi)
        + 10.f * padread(g_T3, 18, d, oi)
        + 5.f  * padread(g_T4, 24, d, oi)
        +        padread(g_T5, 30, d, oi);
    }
    g_Sfrag[((size_t)c*64 + lane)*8 + j] = (__bf16)v;
  }
}

// ---- main kernels ----
__device__ __forceinline__ int ldsIdx(int col, int ch) {
  return col * NCH + (ch ^ ((col & 4) << 1));
}

__global__ __launch_bounds__(256) void transpose_kernel(const float* __restrict__ in,
                                                        float* __restrict__ out) {
  const int b = blockIdx.y;
  const int x = blockIdx.x * 256 + threadIdx.x;
  const float* __restrict__ ib = in + (size_t)b * NCH * LL;
  float* __restrict__ ob = out + (size_t)b * NCH * LL;
  float v[NCH];
#pragma unroll
  for (int c = 0; c < NCH; ++c) v[c] = ib[c * LL + x];
#pragma unroll
  for (int c = 0; c < NCH; c += 4)
    *(float4*)(ob + (size_t)x * NCH + c) = make_float4(v[c], v[c+1], v[c+2], v[c+3]);
}

__device__ __forceinline__ bf16x8 mkA(const float* __restrict__ W, int c, int g, int n) {
  const int kk = c * 2 + (g >> 1);
  bf16x8 a;
#pragma unroll
  for (int j = 0; j < 8; ++j) {
    const int i = (g & 1) * 8 + j;
    a[j] = (__bf16)((kk < 5) ? W[n * (NCH * 5) + i * 5 + kk] : 0.0f);
  }
  return a;
}

__device__ __forceinline__ f32x4 ldState(const float* __restrict__ zb, int x0,
                                         int t, int n, int g) {
  int gx = x0 - HALOC + 16 * t + n;
  gx = min(max(gx, 0), LL - 1);
  return *(const f32x4*)(zb + (size_t)gx * NCH + g * 4);
}

// Edge path (verified R14): one 16-col tile of one RK stage.
template<int MODE, bool UPDZ>
__device__ __forceinline__ void tileStage(
    int t, f32x4& KZ, f32x4& KF, float az, float ak, float agh,
    const __bf16* __restrict__ RS, __bf16* __restrict__ WS,
    bf16x8 af0, bf16x8 af1, bf16x8 af2,
    int lane, int g, int n, bool leftE, bool rightE,
    float* __restrict__ ob, int x0, int finalKer)
{
  f32x4 acc = {0.f, 0.f, 0.f, 0.f};
#pragma unroll
  for (int c = 0; c < 3; ++c) {
    const int kk = c * 2 + (g >> 1);
    int s = 16 * t + n + kk - 2;
    s = min(max(s, 0), SLABC - 1);
    const bf16x8 bfrag = *(const bf16x8*)(&RS[ldsIdx(s, (g & 1) * 8)]);
    const bf16x8 a = (c == 0) ? af0 : (c == 1) ? af1 : af2;
    acc = __builtin_amdgcn_mfma_f32_16x16x32_bf16(a, bfrag, acc, 0, 0, 0);
  }
  f32x4 v;
#pragma unroll
  for (int r = 0; r < 4; ++r) v[r] = az * KZ[r] + ak * KF[r] + agh * acc[r];

  if (leftE && t == 2) {
#pragma unroll
    for (int r = 0; r < 4; ++r) {
      const float sv = __shfl(v[r], (lane & 48) | 10, 64);
      if (n < 10) v[r] = sv;
    }
  }
  if (rightE && t == 9) {
#pragma unroll
    for (int r = 0; r < 4; ++r) {
      const float sv = __shfl(v[r], (lane & 48) | 5, 64);
      if (n > 5) v[r] = sv;
    }
  }

  KF = v;
  if (UPDZ) KZ = v;

  if (MODE == 0) {
    bf16x4 bv = { (__bf16)v[0], (__bf16)v[1], (__bf16)v[2], (__bf16)v[3] };
    *(bf16x4*)(&WS[ldsIdx(16 * t + n, g * 4)]) = bv;
  } else {
    if (t >= 2 && t <= 9) {
      const int xg = x0 - HALOC + 16 * t + n;
      if (!finalKer) {
        *(f32x4*)(ob + (size_t)xg * NCH + g * 4) = v;
      } else {
#pragma unroll
        for (int r = 0; r < 4; ++r) ob[(size_t)(g * 4 + r) * LL + xg] = v[r];
      }
    }
  }
}

#define STAGE(az, ak, agh, UPDZ, MODE)                                          \
  do {                                                                          \
    const __bf16* RS_ = S[rb];                                                  \
    __bf16* WS_ = S[rb ^ 1];                                                    \
    tileStage<MODE, UPDZ>(wv + 0, kz0, kf0, az, ak, agh, RS_, WS_, af0, af1,    \
                          af2, lane, g, n, leftE, rightE, ob, x0, finalKer);    \
    tileStage<MODE, UPDZ>(wv + 4, kz1, kf1, az, ak, agh, RS_, WS_, af0, af1,    \
                          af2, lane, g, n, leftE, rightE, ob, x0, finalKer);    \
    tileStage<MODE, UPDZ>(wv + 8, kz2, kf2, az, ak, agh, RS_, WS_, af0, af1,    \
                          af2, lane, g, n, leftE, rightE, ob, x0, finalKer);    \
  } while (0)

__global__ __launch_bounds__(256)
void multistep_kernel(
    const float* __restrict__ zin,   // fp32 transposed [b][x][ch]
    float* __restrict__ zout,        // fp32 transposed (row-major if finalKer)
    const float* __restrict__ W,     // [o][i][k] 16x16x5
    const int* __restrict__ tptr, int finalKer)
{
  __shared__ __align__(16) __bf16 S[2][SLABC * NCH];   // edge path dbuf
  __shared__ __align__(16) __bf16 ISL[ISLAB * NCH];    // interior slab

  const int b = blockIdx.y, bx = blockIdx.x;
  const int x0 = bx * TX;
  const bool leftE = (bx == 0), rightE = (bx == NBX - 1);
  const int tid = threadIdx.x, lane = tid & 63, wv = tid >> 6;
  const int g = lane >> 4, n = lane & 15;

  const float* __restrict__ zb = zin + (size_t)b * NCH * LL;
  float* __restrict__ ob = zout + (size_t)b * NCH * LL;

  if (leftE || rightE) {
    // ---- exact 15-stage path (boundary clamp), verbatim R14 ----
    const float h = (float)(*tptr) / (float)NSTEPS;
    const bf16x8 af0 = mkA(W, 0, g, n);
    const bf16x8 af1 = mkA(W, 1, g, n);
    const bf16x8 af2 = mkA(W, 2, g, n);

    for (int q = tid; q < SLABC * 4; q += 256) {
      const int s = q >> 2, cg = (q & 3) * 4;
      int gx = x0 - HALOC + s;
      gx = min(max(gx, 0), LL - 1);
      const float4 v = *(const float4*)(zb + (size_t)gx * NCH + cg);
      bf16x4 bv = { (__bf16)v.x, (__bf16)v.y, (__bf16)v.z, (__bf16)v.w };
      *(bf16x4*)(&S[0][ldsIdx(s, cg)]) = bv;
    }

    f32x4 kz0 = ldState(zb, x0, wv + 0, n, g);
    f32x4 kz1 = ldState(zb, x0, wv + 4, n, g);
    f32x4 kz2 = ldState(zb, x0, wv + 8, n, g);
    f32x4 kf0 = {0.f,0.f,0.f,0.f}, kf1 = kf0, kf2 = kf0;
    __syncthreads();

    const float c13 = 1.0f / 3.0f, c23 = 2.0f / 3.0f;
    int rb = 0;
#pragma unroll 1
    for (int sp = 0; sp < SPK; ++sp) {
      STAGE(1.0f, 0.0f, h, false, 0);
      __syncthreads(); rb ^= 1;
      STAGE(0.75f, 0.25f, 0.25f * h, false, 0);
      __syncthreads(); rb ^= 1;
      if (sp != SPK - 1) {
        STAGE(c13, c23, c23 * h, true, 0);
        __syncthreads(); rb ^= 1;
      } else {
        STAGE(c13, c23, c23 * h, true, 1);
      }
    }
  } else {
    // ---- fused interior path: z' = z + S5 z, one conv stage, one barrier ----
    for (int q = tid; q < ISLAB * 4; q += 256) {
      const int s = q >> 2, cg = (q & 3) * 4;
      const int gx = x0 - RAD + s;              // in-range for interior blocks
      const float4 v = *(const float4*)(zb + (size_t)gx * NCH + cg);
      bf16x4 bv = { (__bf16)v.x, (__bf16)v.y, (__bf16)v.z, (__bf16)v.w };
      *(bf16x4*)(&ISL[ldsIdx(s, cg)]) = bv;
    }

    const int o0 = 16 * wv + n;                 // tiles wv and wv+4
    const f32x4 kz0 = *(const f32x4*)(zb + (size_t)(x0 + o0) * NCH + g * 4);
    const f32x4 kz1 = *(const f32x4*)(zb + (size_t)(x0 + o0 + 64) * NCH + g * 4);
    __syncthreads();

    const int p = g >> 1, hsel = g & 1;
    f32x4 acc0 = {0.f,0.f,0.f,0.f}, acc1 = acc0;
    const __bf16* Af = g_Sfrag + (size_t)lane * 8;
    int col0 = o0 + p;                          // slab col for chunk c=0, tile 0
#pragma unroll
    for (int c = 0; c < NCHUNK; ++c) {
      const bf16x8 a = *(const bf16x8*)(Af + (size_t)c * 512);
      const int xr = ((((col0 >> 2) & 1) ^ hsel) << 4);
      const bf16x8 b0 = *(const bf16x8*)((const char*)ISL + col0 * 32 + xr);
      const bf16x8 b1 = *(const bf16x8*)((const char*)ISL + (col0 + 64) * 32 + xr);
      acc0 = __builtin_amdgcn_mfma_f32_16x16x32_bf16(a, b0, acc0, 0, 0, 0);
      acc1 = __builtin_amdgcn_mfma_f32_16x16x32_bf16(a, b1, acc1, 0, 0, 0);
      col0 += 2;
    }

    f32x4 v0, v1;
#pragma unroll
    for (int r = 0; r < 4; ++r) { v0[r] = kz0[r] + acc0[r]; v1[r] = kz1[r] + acc1[r]; }

    if (!finalKer) {
      *(f32x4*)(ob + (size_t)(x0 + o0) * NCH + g * 4) = v0;
      *(f32x4*)(ob + (size_t)(x0 + o0 + 64) * NCH + g * 4) = v1;
    } else {
#pragma unroll
      for (int r = 0; r < 4; ++r) {
        ob[(size_t)(g * 4 + r) * LL + (x0 + o0)] = v0[r];
        ob[(size_t)(g * 4 + r) * LL + (x0 + o0 + 64)] = v1[r];
      }
    }
  }
}

extern "C" void kernel_launch(void* const* d_in, const int* in_sizes, int n_in,
                              void* d_out, int out_size, void* d_ws, size_t ws_size,
                              hipStream_t stream) {
  const float* z0 = (const float*)d_in[0];
  const float* W  = (const float*)d_in[1];
  const int*   t  = (const int*)d_in[2];

  float* Q = (float*)d_out;   // transposed intermediate; final row-major dest
  float* P = (float*)d_ws;    // 16 MiB scratch

  // Build S5 taps (tiny kernels, ~100K MACs total).
  build_G<<<dim3(1), dim3(256), 0, stream>>>(W, t);
  compose_k<<<dim3( 9), dim3(256), 0, stream>>>(0);   // G2 = G*G
  compose_k<<<dim3(13), dim3(256), 0, stream>>>(1);   // G3 = G2*G -> g_Tp
  build_Tp<<<dim3(1), dim3(256), 0, stream>>>();      // T' = G + G2/2 + G3/6
  compose_k<<<dim3(25), dim3(256), 0, stream>>>(2);   // T'^2
  compose_k<<<dim3(37), dim3(256), 0, stream>>>(3);   // T'^3
  compose_k<<<dim3(49), dim3(256), 0, stream>>>(4);   // T'^4
  compose_k<<<dim3(61), dim3(256), 0, stream>>>(5);   // T'^5
  pack_S<<<dim3(NCHUNK), dim3(256), 0, stream>>>();

  dim3 block(256);
  transpose_kernel<<<dim3(32, NB), block, 0, stream>>>(z0, Q);

  dim3 mgrid(NBX, NB);
  for (int k = 1; k <= NKER; ++k) {
    if (k & 1) multistep_kernel<<<mgrid, block, 0, stream>>>(Q, P, W, t, 0);
    else       multistep_kernel<<<mgrid, block, 0, stream>>>(P, Q, W, t, k == NKER);
  }
}